// Round 3
// baseline (2621.060 us; speedup 1.0000x reference)
//
#include <hip/hip_runtime.h>
#include <hip/hip_bf16.h>

#define N_NODES 50000
#define N_EDGES 800000
#define NPATH 3
#define NB 16

// ---------------------------------------------------------------------------
// Kernel 1: feat = h @ W  (50000x128 @ 128x256), fused el/er head reductions.
// Block = 256 threads = one column each; NB=16 nodes per block (3125 blocks).
// ---------------------------------------------------------------------------
__global__ __launch_bounds__(256) void feat_gemm_kernel(
    const float* __restrict__ h,
    const float* __restrict__ W,     // 128x256 (path slice)
    const float* __restrict__ al,    // 256 (=8x32 flat, path slice)
    const float* __restrict__ ar,
    float* __restrict__ feat,        // N x 256
    float* __restrict__ el,          // N x 8
    float* __restrict__ er) {
  __shared__ float a_tile[NB][128];
  const int t = threadIdx.x;
  const int nb = blockIdx.x * NB;

  for (int i = t; i < NB * 128; i += 256) {
    int n = i >> 7, k = i & 127;
    a_tile[n][k] = h[(size_t)(nb + n) * 128 + k];
  }
  __syncthreads();

  const int c = t;  // output column 0..255
  float acc[NB];
#pragma unroll
  for (int n = 0; n < NB; n++) acc[n] = 0.f;

  for (int k = 0; k < 128; k += 4) {
    float w0 = W[(k + 0) * 256 + c];
    float w1 = W[(k + 1) * 256 + c];
    float w2 = W[(k + 2) * 256 + c];
    float w3 = W[(k + 3) * 256 + c];
#pragma unroll
    for (int n = 0; n < NB; n++) {
      float4 a4 = *(const float4*)&a_tile[n][k];
      acc[n] = fmaf(a4.x, w0, acc[n]);
      acc[n] = fmaf(a4.y, w1, acc[n]);
      acc[n] = fmaf(a4.z, w2, acc[n]);
      acc[n] = fmaf(a4.w, w3, acc[n]);
    }
  }

  const float alc = al[c];
  const float arc = ar[c];
  const int lane = t & 31;
  const int hh = c >> 5;  // head 0..7

#pragma unroll
  for (int n = 0; n < NB; n++) {
    const int node = nb + n;
    feat[(size_t)node * 256 + c] = acc[n];
    float pl = acc[n] * alc;
    float pr = acc[n] * arc;
#pragma unroll
    for (int off = 16; off > 0; off >>= 1) {
      pl += __shfl_down(pl, off, 32);
      pr += __shfl_down(pr, off, 32);
    }
    if (lane == 0) {
      el[node * 8 + hh] = pl;
      er[node * 8 + hh] = pr;
    }
  }
}

// ---------------------------------------------------------------------------
// Kernel 2: per (edge, head): ex = exp(leaky_relu(el[src]+er[dst])),
// store ex, atomic-accumulate softmax denominator per (dst, head).
// segment_max skipped: softmax is shift-invariant; |el+er| is O(1) here so
// exp cannot overflow.
// ---------------------------------------------------------------------------
__global__ __launch_bounds__(256) void edge_attn_kernel(
    const int* __restrict__ src, const int* __restrict__ dst,
    const float* __restrict__ el, const float* __restrict__ er,
    float* __restrict__ aex, float* __restrict__ den) {
  int idx = blockIdx.x * 256 + threadIdx.x;
  if (idx >= N_EDGES * 8) return;
  int e = idx >> 3, hh = idx & 7;
  int s = src[e], d = dst[e];
  float x = el[s * 8 + hh] + er[d * 8 + hh];
  x = x > 0.f ? x : 0.2f * x;
  float ex = expf(x);
  aex[idx] = ex;
  unsafeAtomicAdd(&den[d * 8 + hh], ex);
}

// ---------------------------------------------------------------------------
// Kernel 3: scatter msg = a * feat[src] into agg[dst].
// 32 lanes per edge (one per d), loop over 8 heads. 256 atomics/edge.
// ---------------------------------------------------------------------------
__global__ __launch_bounds__(256) void edge_aggr_kernel(
    const int* __restrict__ src, const int* __restrict__ dst,
    const float* __restrict__ aex, const float* __restrict__ den,
    const float* __restrict__ feat, float* __restrict__ agg) {
  const int t = threadIdx.x;
  const int e = blockIdx.x * 8 + (t >> 5);
  if (e >= N_EDGES) return;
  const int l = t & 31;
  const int s = src[e], d = dst[e];
  const float* fb = feat + (size_t)s * 256;
  float* ob = agg + (size_t)d * 256;
#pragma unroll
  for (int hh = 0; hh < 8; hh++) {
    float w = aex[e * 8 + hh] / den[d * 8 + hh];
    float v = fb[hh * 32 + l];
    unsafeAtomicAdd(&ob[hh * 32 + l], w * v);
  }
}

// ---------------------------------------------------------------------------
// Kernel 4: out += elu(agg) @ sem_w[pathslice]  (50000x256 @ 256x128).
// d_out (f32) doubles as the cross-path accumulator.
// mode 0: first path (init with bias), else: accumulate.
// ---------------------------------------------------------------------------
__global__ __launch_bounds__(256) void sem_gemm_kernel(
    const float* __restrict__ agg,
    const float* __restrict__ Ws,    // 256x128 (path slice)
    const float* __restrict__ bias,  // 128
    float* __restrict__ out, int mode) {
  __shared__ float a_tile[NB][256];
  const int t = threadIdx.x;
  const int nb = blockIdx.x * NB;

  for (int i = t; i < NB * 256; i += 256) {
    int n = i >> 8, k = i & 255;
    float x = agg[(size_t)(nb + n) * 256 + k];
    a_tile[n][k] = x > 0.f ? x : (expf(x) - 1.f);  // elu
  }
  __syncthreads();

  const int c = t & 127;
  const int half = t >> 7;
  float acc[8];
#pragma unroll
  for (int i = 0; i < 8; i++) acc[i] = 0.f;

  for (int k = 0; k < 256; k += 4) {
    float w0 = Ws[(k + 0) * 128 + c];
    float w1 = Ws[(k + 1) * 128 + c];
    float w2 = Ws[(k + 2) * 128 + c];
    float w3 = Ws[(k + 3) * 128 + c];
#pragma unroll
    for (int i = 0; i < 8; i++) {
      float4 a4 = *(const float4*)&a_tile[half * 8 + i][k];
      acc[i] = fmaf(a4.x, w0, acc[i]);
      acc[i] = fmaf(a4.y, w1, acc[i]);
      acc[i] = fmaf(a4.z, w2, acc[i]);
      acc[i] = fmaf(a4.w, w3, acc[i]);
    }
  }

#pragma unroll
  for (int i = 0; i < 8; i++) {
    const int node = nb + half * 8 + i;
    const size_t o = (size_t)node * 128 + c;
    float r = acc[i];
    if (mode == 0) r += bias[c];
    else r += out[o];
    out[o] = r;
  }
}

// ---------------------------------------------------------------------------
extern "C" void kernel_launch(void* const* d_in, const int* in_sizes, int n_in,
                              void* d_out, int out_size, void* d_ws, size_t ws_size,
                              hipStream_t stream) {
  const float* h      = (const float*)d_in[0];
  const int*   ei     = (const int*)d_in[1];
  const float* fc_w   = (const float*)d_in[2];
  const float* attn_l = (const float*)d_in[3];
  const float* attn_r = (const float*)d_in[4];
  const float* sem_w  = (const float*)d_in[5];
  const float* sem_b  = (const float*)d_in[6];
  float* out = (float*)d_out;   // f32 output (reference returns float32)

  // workspace layout (bytes) — total 132.8 MB (no-fault confirmed R1/R2)
  char* ws = (char*)d_ws;
  float* feat = (float*)ws;                                   // 51.2 MB
  float* agg  = (float*)(ws + 51200000);                      // 51.2 MB
  float* el   = (float*)(ws + 102400000);                     // 1.6 MB
  float* er   = (float*)(ws + 104000000);                     // 1.6 MB
  float* den  = (float*)(ws + 105600000);                     // 1.6 MB
  float* aex  = (float*)(ws + 107200000);                     // 25.6 MB

  for (int p = 0; p < NPATH; p++) {
    const int* src = ei + (size_t)p * 2 * N_EDGES;
    const int* dst = src + N_EDGES;

    hipMemsetAsync(den, 0, (size_t)N_NODES * 8 * sizeof(float), stream);
    feat_gemm_kernel<<<N_NODES / NB, 256, 0, stream>>>(
        h, fc_w + (size_t)p * 128 * 256, attn_l + p * 256, attn_r + p * 256,
        feat, el, er);
    edge_attn_kernel<<<(N_EDGES * 8 + 255) / 256, 256, 0, stream>>>(
        src, dst, el, er, aex, den);
    hipMemsetAsync(agg, 0, (size_t)N_NODES * 256 * sizeof(float), stream);
    edge_aggr_kernel<<<N_EDGES / 8, 256, 0, stream>>>(
        src, dst, aex, den, feat, agg);
    sem_gemm_kernel<<<N_NODES / NB, 256, 0, stream>>>(
        agg, sem_w + (size_t)p * 256 * 128, sem_b, out, p);
  }
}

// Round 4
// 1280.814 us; speedup vs baseline: 2.0464x; 2.0464x over previous
//
#include <hip/hip_runtime.h>
#include <hip/hip_bf16.h>

#define N_NODES 50000
#define N_EDGES 800000
#define NPATH 3
#define NB 16

// ---------------------------------------------------------------------------
// CSR build (all 3 paths up front): histogram -> per-path scan -> scatter.
// ---------------------------------------------------------------------------
__global__ __launch_bounds__(256) void hist3_kernel(
    const int* __restrict__ ei, int* __restrict__ deg) {
  int idx = blockIdx.x * 256 + threadIdx.x;
  if (idx >= NPATH * N_EDGES) return;
  int p = idx / N_EDGES, e = idx - p * N_EDGES;
  int d = ei[p * 2 * N_EDGES + N_EDGES + e];
  atomicAdd(&deg[p * N_NODES + d], 1);
}

// 3 blocks, one per path; sequential 1024-chunk scan with carry.
__global__ __launch_bounds__(1024) void scan3_kernel(
    const int* __restrict__ deg, int* __restrict__ off, int* __restrict__ cur) {
  __shared__ int tmp[1024];
  __shared__ int carry;
  const int p = blockIdx.x;
  const int t = threadIdx.x;
  const int* dg = deg + p * N_NODES;
  int* of = off + p * N_NODES;
  int* cu = cur + p * N_NODES;
  if (t == 0) carry = 0;
  __syncthreads();
  for (int base = 0; base < N_NODES; base += 1024) {
    int i = base + t;
    int v = (i < N_NODES) ? dg[i] : 0;
    tmp[t] = v;
    __syncthreads();
    for (int ofs = 1; ofs < 1024; ofs <<= 1) {
      int x = (t >= ofs) ? tmp[t - ofs] : 0;
      __syncthreads();
      tmp[t] += x;
      __syncthreads();
    }
    int excl = carry + tmp[t] - v;   // reads carry (previous iteration's)
    if (i < N_NODES) { of[i] = excl; cu[i] = excl; }
    int total = tmp[1023];
    __syncthreads();                 // all carry-reads done before update
    if (t == 0) carry += total;
    __syncthreads();
  }
}

__global__ __launch_bounds__(256) void scatter3_kernel(
    const int* __restrict__ ei, int* __restrict__ cur, int* __restrict__ csr_src) {
  int idx = blockIdx.x * 256 + threadIdx.x;
  if (idx >= NPATH * N_EDGES) return;
  int p = idx / N_EDGES, e = idx - p * N_EDGES;
  int s = ei[p * 2 * N_EDGES + e];
  int d = ei[p * 2 * N_EDGES + N_EDGES + e];
  int pos = atomicAdd(&cur[p * N_NODES + d], 1);
  csr_src[p * N_EDGES + pos] = s;
}

// ---------------------------------------------------------------------------
// Kernel 1: feat = h @ W  (50000x128 @ 128x256), fused el/er head reductions.
// ---------------------------------------------------------------------------
__global__ __launch_bounds__(256) void feat_gemm_kernel(
    const float* __restrict__ h,
    const float* __restrict__ W,     // 128x256 (path slice)
    const float* __restrict__ al,    // 256 flat (8x32, path slice)
    const float* __restrict__ ar,
    float* __restrict__ feat,        // N x 256
    float* __restrict__ el,          // N x 8
    float* __restrict__ er) {
  __shared__ float a_tile[NB][128];
  const int t = threadIdx.x;
  const int nb = blockIdx.x * NB;

  for (int i = t; i < NB * 128; i += 256) {
    int n = i >> 7, k = i & 127;
    a_tile[n][k] = h[(size_t)(nb + n) * 128 + k];
  }
  __syncthreads();

  const int c = t;
  float acc[NB];
#pragma unroll
  for (int n = 0; n < NB; n++) acc[n] = 0.f;

  for (int k = 0; k < 128; k += 4) {
    float w0 = W[(k + 0) * 256 + c];
    float w1 = W[(k + 1) * 256 + c];
    float w2 = W[(k + 2) * 256 + c];
    float w3 = W[(k + 3) * 256 + c];
#pragma unroll
    for (int n = 0; n < NB; n++) {
      float4 a4 = *(const float4*)&a_tile[n][k];
      acc[n] = fmaf(a4.x, w0, acc[n]);
      acc[n] = fmaf(a4.y, w1, acc[n]);
      acc[n] = fmaf(a4.z, w2, acc[n]);
      acc[n] = fmaf(a4.w, w3, acc[n]);
    }
  }

  const float alc = al[c];
  const float arc = ar[c];
  const int lane = t & 31;
  const int hh = c >> 5;

#pragma unroll
  for (int n = 0; n < NB; n++) {
    const int node = nb + n;
    feat[(size_t)node * 256 + c] = acc[n];
    float pl = acc[n] * alc;
    float pr = acc[n] * arc;
#pragma unroll
    for (int off = 16; off > 0; off >>= 1) {
      pl += __shfl_down(pl, off, 32);
      pr += __shfl_down(pr, off, 32);
    }
    if (lane == 0) {
      el[node * 8 + hh] = pl;
      er[node * 8 + hh] = pr;
    }
  }
}

// ---------------------------------------------------------------------------
// Kernel 2 (NEW): per-dst gather-aggregate, softmax fused in one pass:
//   agg[d] = (sum_e ex_e * feat[src_e]) / (sum_e ex_e),  ex = exp(leaky(el+er))
// One block (256 thr = channels) per dst node; no atomics; writes elu(agg).
// ---------------------------------------------------------------------------
__global__ __launch_bounds__(256) void aggregate_kernel(
    const int* __restrict__ csr_src, const int* __restrict__ off,
    const int* __restrict__ deg,
    const float* __restrict__ el, const float* __restrict__ er,
    const float* __restrict__ feat, float* __restrict__ eagg) {
  const int d = blockIdx.x;
  const int t = threadIdx.x;       // channel 0..255
  const int h = t >> 5;            // head
  const float erh = er[d * 8 + h];
  const int start = off[d];
  const int n = deg[d];
  const int* lst = csr_src + start;

  float accN = 0.f, accD = 0.f;
  int j = 0;
  for (; j + 4 <= n; j += 4) {
    int s0 = lst[j + 0], s1 = lst[j + 1], s2 = lst[j + 2], s3 = lst[j + 3];
    float x0 = el[s0 * 8 + h] + erh;
    float x1 = el[s1 * 8 + h] + erh;
    float x2 = el[s2 * 8 + h] + erh;
    float x3 = el[s3 * 8 + h] + erh;
    float v0 = feat[s0 * 256 + t];
    float v1 = feat[s1 * 256 + t];
    float v2 = feat[s2 * 256 + t];
    float v3 = feat[s3 * 256 + t];
    x0 = x0 > 0.f ? x0 : 0.2f * x0;  float e0 = __expf(x0);
    x1 = x1 > 0.f ? x1 : 0.2f * x1;  float e1 = __expf(x1);
    x2 = x2 > 0.f ? x2 : 0.2f * x2;  float e2 = __expf(x2);
    x3 = x3 > 0.f ? x3 : 0.2f * x3;  float e3 = __expf(x3);
    accN = fmaf(e0, v0, accN);  accD += e0;
    accN = fmaf(e1, v1, accN);  accD += e1;
    accN = fmaf(e2, v2, accN);  accD += e2;
    accN = fmaf(e3, v3, accN);  accD += e3;
  }
  for (; j < n; j++) {
    int s = lst[j];
    float x = el[s * 8 + h] + erh;
    x = x > 0.f ? x : 0.2f * x;
    float ex = __expf(x);
    accN = fmaf(ex, feat[s * 256 + t], accN);
    accD += ex;
  }

  float r = (n > 0) ? accN / accD : 0.f;
  r = r > 0.f ? r : (__expf(r) - 1.f);   // elu fused here
  eagg[(size_t)d * 256 + t] = r;
}

// ---------------------------------------------------------------------------
// Kernel 3: out += eagg @ sem_w[pathslice]  (50000x256 @ 256x128), f32 out.
// d_out doubles as the cross-path accumulator. mode 0: init with bias.
// ---------------------------------------------------------------------------
__global__ __launch_bounds__(256) void sem_gemm_kernel(
    const float* __restrict__ eagg,
    const float* __restrict__ Ws,    // 256x128 (path slice)
    const float* __restrict__ bias,  // 128
    float* __restrict__ out, int mode) {
  __shared__ float a_tile[NB][256];
  const int t = threadIdx.x;
  const int nb = blockIdx.x * NB;

  for (int i = t; i < NB * 256; i += 256) {
    int n = i >> 8, k = i & 255;
    a_tile[n][k] = eagg[(size_t)(nb + n) * 256 + k];
  }
  __syncthreads();

  const int c = t & 127;
  const int half = t >> 7;
  float acc[8];
#pragma unroll
  for (int i = 0; i < 8; i++) acc[i] = 0.f;

  for (int k = 0; k < 256; k += 4) {
    float w0 = Ws[(k + 0) * 128 + c];
    float w1 = Ws[(k + 1) * 128 + c];
    float w2 = Ws[(k + 2) * 128 + c];
    float w3 = Ws[(k + 3) * 128 + c];
#pragma unroll
    for (int i = 0; i < 8; i++) {
      float4 a4 = *(const float4*)&a_tile[half * 8 + i][k];
      acc[i] = fmaf(a4.x, w0, acc[i]);
      acc[i] = fmaf(a4.y, w1, acc[i]);
      acc[i] = fmaf(a4.z, w2, acc[i]);
      acc[i] = fmaf(a4.w, w3, acc[i]);
    }
  }

#pragma unroll
  for (int i = 0; i < 8; i++) {
    const int node = nb + half * 8 + i;
    const size_t o = (size_t)node * 128 + c;
    float r = acc[i];
    if (mode == 0) r += bias[c];
    else r += out[o];
    out[o] = r;
  }
}

// ---------------------------------------------------------------------------
extern "C" void kernel_launch(void* const* d_in, const int* in_sizes, int n_in,
                              void* d_out, int out_size, void* d_ws, size_t ws_size,
                              hipStream_t stream) {
  const float* h      = (const float*)d_in[0];
  const int*   ei     = (const int*)d_in[1];
  const float* fc_w   = (const float*)d_in[2];
  const float* attn_l = (const float*)d_in[3];
  const float* attn_r = (const float*)d_in[4];
  const float* sem_w  = (const float*)d_in[5];
  const float* sem_b  = (const float*)d_in[6];
  float* out = (float*)d_out;

  // workspace layout (bytes) — total 117.0 MB (<=132.8 MB proven safe R1/R2)
  char* ws = (char*)d_ws;
  float* feat    = (float*)ws;                       // 51.2 MB
  float* eagg    = (float*)(ws + 51200000);          // 51.2 MB
  float* el      = (float*)(ws + 102400000);         // 1.6 MB
  float* er      = (float*)(ws + 104000000);         // 1.6 MB
  int*   deg3    = (int*)(ws + 105600000);           // 0.6 MB
  int*   off3    = (int*)(ws + 106200000);           // 0.6 MB
  int*   cur3    = (int*)(ws + 106800000);           // 0.6 MB
  int*   csr_src = (int*)(ws + 107400000);           // 9.6 MB

  // --- CSR build for all 3 paths ---
  hipMemsetAsync(deg3, 0, (size_t)NPATH * N_NODES * sizeof(int), stream);
  hist3_kernel<<<(NPATH * N_EDGES + 255) / 256, 256, 0, stream>>>(ei, deg3);
  scan3_kernel<<<NPATH, 1024, 0, stream>>>(deg3, off3, cur3);
  scatter3_kernel<<<(NPATH * N_EDGES + 255) / 256, 256, 0, stream>>>(ei, cur3, csr_src);

  for (int p = 0; p < NPATH; p++) {
    feat_gemm_kernel<<<N_NODES / NB, 256, 0, stream>>>(
        h, fc_w + (size_t)p * 128 * 256, attn_l + p * 256, attn_r + p * 256,
        feat, el, er);
    aggregate_kernel<<<N_NODES, 256, 0, stream>>>(
        csr_src + (size_t)p * N_EDGES, off3 + p * N_NODES, deg3 + p * N_NODES,
        el, er, feat, eagg);
    sem_gemm_kernel<<<N_NODES / NB, 256, 0, stream>>>(
        eagg, sem_w + (size_t)p * 256 * 128, sem_b, out, p);
  }
}

// Round 5
// 981.874 us; speedup vs baseline: 2.6694x; 1.3045x over previous
//
#include <hip/hip_runtime.h>
#include <hip/hip_bf16.h>

#define N_NODES 50000
#define N_EDGES 800000
#define NPATH 3

typedef __attribute__((ext_vector_type(8))) short short8;
typedef __attribute__((ext_vector_type(4))) float v4f;

// ---------------------------------------------------------------------------
// CSR build (unchanged from R4): histogram -> per-path scan -> scatter.
// ---------------------------------------------------------------------------
__global__ __launch_bounds__(256) void hist3_kernel(
    const int* __restrict__ ei, int* __restrict__ deg) {
  int idx = blockIdx.x * 256 + threadIdx.x;
  if (idx >= NPATH * N_EDGES) return;
  int p = idx / N_EDGES, e = idx - p * N_EDGES;
  int d = ei[p * 2 * N_EDGES + N_EDGES + e];
  atomicAdd(&deg[p * N_NODES + d], 1);
}

__global__ __launch_bounds__(1024) void scan3_kernel(
    const int* __restrict__ deg, int* __restrict__ off, int* __restrict__ cur) {
  __shared__ int tmp[1024];
  __shared__ int carry;
  const int p = blockIdx.x;
  const int t = threadIdx.x;
  const int* dg = deg + p * N_NODES;
  int* of = off + p * N_NODES;
  int* cu = cur + p * N_NODES;
  if (t == 0) carry = 0;
  __syncthreads();
  for (int base = 0; base < N_NODES; base += 1024) {
    int i = base + t;
    int v = (i < N_NODES) ? dg[i] : 0;
    tmp[t] = v;
    __syncthreads();
    for (int ofs = 1; ofs < 1024; ofs <<= 1) {
      int x = (t >= ofs) ? tmp[t - ofs] : 0;
      __syncthreads();
      tmp[t] += x;
      __syncthreads();
    }
    int excl = carry + tmp[t] - v;
    if (i < N_NODES) { of[i] = excl; cu[i] = excl; }
    int total = tmp[1023];
    __syncthreads();
    if (t == 0) carry += total;
    __syncthreads();
  }
}

__global__ __launch_bounds__(256) void scatter3_kernel(
    const int* __restrict__ ei, int* __restrict__ cur, int* __restrict__ csr_src) {
  int idx = blockIdx.x * 256 + threadIdx.x;
  if (idx >= NPATH * N_EDGES) return;
  int p = idx / N_EDGES, e = idx - p * N_EDGES;
  int s = ei[p * 2 * N_EDGES + e];
  int d = ei[p * 2 * N_EDGES + N_EDGES + e];
  int pos = atomicAdd(&cur[p * N_NODES + d], 1);
  csr_src[p * N_EDGES + pos] = s;
}

// ---------------------------------------------------------------------------
// h split: h_hi = bf16(h), h_lo = bf16(h - h_hi). Once per launch.
// ---------------------------------------------------------------------------
__global__ __launch_bounds__(256) void hsplit_kernel(
    const float* __restrict__ h,
    __hip_bfloat16* __restrict__ h_hi, __hip_bfloat16* __restrict__ h_lo) {
  int i = blockIdx.x * 256 + threadIdx.x;
  if (i >= N_NODES * 128) return;
  float v = h[i];
  __hip_bfloat16 hb = __float2bfloat16(v);
  h_hi[i] = hb;
  h_lo[i] = __float2bfloat16(v - __bfloat162float(hb));
}

// ---------------------------------------------------------------------------
// Per-path prep 1: Walr[k][c] (128x16): c<8 -> W@al (head c), c>=8 -> W@ar.
// el = h @ (W@al) by associativity — keeps attention logits f32-exact.
// ---------------------------------------------------------------------------
__global__ __launch_bounds__(256) void walr_kernel(
    const float* __restrict__ W, const float* __restrict__ al,
    const float* __restrict__ ar, float* __restrict__ Walr) {
  int idx = blockIdx.x * 256 + threadIdx.x;
  if (idx >= 128 * 16) return;
  int k = idx >> 4, c = idx & 15;
  int h8 = c & 7;
  const float* av = (c < 8) ? al : ar;
  float s = 0.f;
  for (int d = 0; d < 32; d++)
    s = fmaf(W[k * 256 + h8 * 32 + d], av[h8 * 32 + d], s);
  Walr[k * 16 + c] = s;
}

// ---------------------------------------------------------------------------
// Per-path prep 2: W fragments (17 N-tiles: 16 from W, tile 16 = Walr),
// permuted to MFMA B-operand order: B[k=quad*8+j][n=l15], hi/lo split.
// Layout: Wf[((kc*17+nt)*64+lane)*8 + j]
// ---------------------------------------------------------------------------
__global__ __launch_bounds__(256) void wfrag_kernel(
    const float* __restrict__ W, const float* __restrict__ Walr,
    __hip_bfloat16* __restrict__ Wf_hi, __hip_bfloat16* __restrict__ Wf_lo) {
  int idx = blockIdx.x * 256 + threadIdx.x;
  if (idx >= 4 * 17 * 64) return;
  int lane = idx & 63;
  int tmp = idx >> 6;            // kc*17 + nt
  int nt = tmp % 17, kc = tmp / 17;
  int l15 = lane & 15, quad = lane >> 4;
  for (int j = 0; j < 8; j++) {
    int k = kc * 32 + quad * 8 + j;
    float v = (nt < 16) ? W[k * 256 + nt * 16 + l15] : Walr[k * 16 + l15];
    __hip_bfloat16 hb = __float2bfloat16(v);
    Wf_hi[(tmp * 64 + lane) * 8 + j] = hb;
    Wf_lo[(tmp * 64 + lane) * 8 + j] = __float2bfloat16(v - __bfloat162float(hb));
  }
}

// ---------------------------------------------------------------------------
// Per-path prep 3: sem_w fragments (8 kc x 8 nt), same B-operand order.
// ---------------------------------------------------------------------------
__global__ __launch_bounds__(256) void bsem_kernel(
    const float* __restrict__ Ws,   // 256x128 path slice
    __hip_bfloat16* __restrict__ Bs_hi, __hip_bfloat16* __restrict__ Bs_lo) {
  int idx = blockIdx.x * 256 + threadIdx.x;
  if (idx >= 8 * 8 * 64) return;
  int lane = idx & 63;
  int tmp = idx >> 6;            // kc*8 + nt
  int nt = tmp & 7, kc = tmp >> 3;
  int l15 = lane & 15, quad = lane >> 4;
  for (int j = 0; j < 8; j++) {
    int k = kc * 32 + quad * 8 + j;
    float v = Ws[k * 128 + nt * 16 + l15];
    __hip_bfloat16 hb = __float2bfloat16(v);
    Bs_hi[(tmp * 64 + lane) * 8 + j] = hb;
    Bs_lo[(tmp * 64 + lane) * 8 + j] = __float2bfloat16(v - __bfloat162float(hb));
  }
}

// ---------------------------------------------------------------------------
// MFMA 1: feat = h @ W (bf16x3), 17th N-tile = [el|er]. 1 wave / 16 rows.
// ---------------------------------------------------------------------------
__global__ __launch_bounds__(64) void feat_mfma_kernel(
    const __hip_bfloat16* __restrict__ h_hi, const __hip_bfloat16* __restrict__ h_lo,
    const __hip_bfloat16* __restrict__ Wf_hi, const __hip_bfloat16* __restrict__ Wf_lo,
    __hip_bfloat16* __restrict__ feat, float* __restrict__ el, float* __restrict__ er) {
  const int lane = threadIdx.x;
  const int l15 = lane & 15, quad = lane >> 4;
  const int m0 = blockIdx.x * 16;
  const int mrow = m0 + l15;

  v4f acc[17];
#pragma unroll
  for (int nt = 0; nt < 17; nt++) acc[nt] = {0.f, 0.f, 0.f, 0.f};

#pragma unroll
  for (int kc = 0; kc < 4; kc++) {
    short8 ahi = *(const short8*)(h_hi + mrow * 128 + kc * 32 + quad * 8);
    short8 alo = *(const short8*)(h_lo + mrow * 128 + kc * 32 + quad * 8);
#pragma unroll
    for (int nt = 0; nt < 17; nt++) {
      const int o = ((kc * 17 + nt) * 64 + lane) * 8;
      short8 bhi = *(const short8*)(Wf_hi + o);
      short8 blo = *(const short8*)(Wf_lo + o);
      acc[nt] = __builtin_amdgcn_mfma_f32_16x16x32_bf16(ahi, bhi, acc[nt], 0, 0, 0);
      acc[nt] = __builtin_amdgcn_mfma_f32_16x16x32_bf16(ahi, blo, acc[nt], 0, 0, 0);
      acc[nt] = __builtin_amdgcn_mfma_f32_16x16x32_bf16(alo, bhi, acc[nt], 0, 0, 0);
    }
  }

#pragma unroll
  for (int nt = 0; nt < 16; nt++)
#pragma unroll
    for (int r = 0; r < 4; r++) {
      int m = m0 + quad * 4 + r;
      feat[(size_t)m * 256 + nt * 16 + l15] = __float2bfloat16(acc[nt][r]);
    }
#pragma unroll
  for (int r = 0; r < 4; r++) {
    int m = m0 + quad * 4 + r;
    float v = acc[16][r];
    if (l15 < 8) el[m * 8 + l15] = v;
    else         er[m * 8 + (l15 - 8)] = v;
  }
}

// ---------------------------------------------------------------------------
// Aggregate (gather, fused softmax + elu), feat is bf16 now; epilogue writes
// eagg pre-split hi/lo for the sem MFMA.
// ---------------------------------------------------------------------------
__global__ __launch_bounds__(256) void aggregate_kernel(
    const int* __restrict__ csr_src, const int* __restrict__ off,
    const int* __restrict__ deg,
    const float* __restrict__ el, const float* __restrict__ er,
    const __hip_bfloat16* __restrict__ feat,
    __hip_bfloat16* __restrict__ eagg_hi, __hip_bfloat16* __restrict__ eagg_lo) {
  const int d = blockIdx.x;
  const int t = threadIdx.x;       // channel 0..255
  const int h = t >> 5;            // head
  const float erh = er[d * 8 + h];
  const int start = off[d];
  const int n = deg[d];
  const int* lst = csr_src + start;

  float accN = 0.f, accD = 0.f;
  int j = 0;
  for (; j + 4 <= n; j += 4) {
    int s0 = lst[j + 0], s1 = lst[j + 1], s2 = lst[j + 2], s3 = lst[j + 3];
    float x0 = el[s0 * 8 + h] + erh;
    float x1 = el[s1 * 8 + h] + erh;
    float x2 = el[s2 * 8 + h] + erh;
    float x3 = el[s3 * 8 + h] + erh;
    float v0 = __bfloat162float(feat[(size_t)s0 * 256 + t]);
    float v1 = __bfloat162float(feat[(size_t)s1 * 256 + t]);
    float v2 = __bfloat162float(feat[(size_t)s2 * 256 + t]);
    float v3 = __bfloat162float(feat[(size_t)s3 * 256 + t]);
    x0 = x0 > 0.f ? x0 : 0.2f * x0;  float e0 = __expf(x0);
    x1 = x1 > 0.f ? x1 : 0.2f * x1;  float e1 = __expf(x1);
    x2 = x2 > 0.f ? x2 : 0.2f * x2;  float e2 = __expf(x2);
    x3 = x3 > 0.f ? x3 : 0.2f * x3;  float e3 = __expf(x3);
    accN = fmaf(e0, v0, accN);  accD += e0;
    accN = fmaf(e1, v1, accN);  accD += e1;
    accN = fmaf(e2, v2, accN);  accD += e2;
    accN = fmaf(e3, v3, accN);  accD += e3;
  }
  for (; j < n; j++) {
    int s = lst[j];
    float x = el[s * 8 + h] + erh;
    x = x > 0.f ? x : 0.2f * x;
    float ex = __expf(x);
    accN = fmaf(ex, __bfloat162float(feat[(size_t)s * 256 + t]), accN);
    accD += ex;
  }

  float r = (n > 0) ? accN / accD : 0.f;
  r = r > 0.f ? r : (__expf(r) - 1.f);   // elu
  __hip_bfloat16 hb = __float2bfloat16(r);
  eagg_hi[(size_t)d * 256 + t] = hb;
  eagg_lo[(size_t)d * 256 + t] = __float2bfloat16(r - __bfloat162float(hb));
}

// ---------------------------------------------------------------------------
// MFMA 2: out (+)= eagg @ sem_w (bf16x3). mode 0: init with bias.
// ---------------------------------------------------------------------------
__global__ __launch_bounds__(64) void sem_mfma_kernel(
    const __hip_bfloat16* __restrict__ eagg_hi, const __hip_bfloat16* __restrict__ eagg_lo,
    const __hip_bfloat16* __restrict__ Bs_hi, const __hip_bfloat16* __restrict__ Bs_lo,
    const float* __restrict__ bias, float* __restrict__ out, int mode) {
  const int lane = threadIdx.x;
  const int l15 = lane & 15, quad = lane >> 4;
  const int m0 = blockIdx.x * 16;
  const int mrow = m0 + l15;

  v4f acc[8];
#pragma unroll
  for (int nt = 0; nt < 8; nt++) acc[nt] = {0.f, 0.f, 0.f, 0.f};

#pragma unroll
  for (int kc = 0; kc < 8; kc++) {
    short8 ahi = *(const short8*)(eagg_hi + (size_t)mrow * 256 + kc * 32 + quad * 8);
    short8 alo = *(const short8*)(eagg_lo + (size_t)mrow * 256 + kc * 32 + quad * 8);
#pragma unroll
    for (int nt = 0; nt < 8; nt++) {
      const int o = ((kc * 8 + nt) * 64 + lane) * 8;
      short8 bhi = *(const short8*)(Bs_hi + o);
      short8 blo = *(const short8*)(Bs_lo + o);
      acc[nt] = __builtin_amdgcn_mfma_f32_16x16x32_bf16(ahi, bhi, acc[nt], 0, 0, 0);
      acc[nt] = __builtin_amdgcn_mfma_f32_16x16x32_bf16(ahi, blo, acc[nt], 0, 0, 0);
      acc[nt] = __builtin_amdgcn_mfma_f32_16x16x32_bf16(alo, bhi, acc[nt], 0, 0, 0);
    }
  }

#pragma unroll
  for (int nt = 0; nt < 8; nt++)
#pragma unroll
    for (int r = 0; r < 4; r++) {
      int m = m0 + quad * 4 + r;
      size_t o = (size_t)m * 128 + nt * 16 + l15;
      float v = acc[nt][r];
      if (mode == 0) v += bias[nt * 16 + l15];
      else           v += out[o];
      out[o] = v;
    }
}

// ---------------------------------------------------------------------------
extern "C" void kernel_launch(void* const* d_in, const int* in_sizes, int n_in,
                              void* d_out, int out_size, void* d_ws, size_t ws_size,
                              hipStream_t stream) {
  const float* h      = (const float*)d_in[0];
  const int*   ei     = (const int*)d_in[1];
  const float* fc_w   = (const float*)d_in[2];
  const float* attn_l = (const float*)d_in[3];
  const float* attn_r = (const float*)d_in[4];
  const float* sem_w  = (const float*)d_in[5];
  const float* sem_b  = (const float*)d_in[6];
  float* out = (float*)d_out;

  // workspace layout (bytes) — total ~117.5 MB (<=132.8 MB proven safe R1/R2)
  char* ws = (char*)d_ws;
  __hip_bfloat16* h_hi    = (__hip_bfloat16*)ws;                   // 12.8 MB
  __hip_bfloat16* h_lo    = (__hip_bfloat16*)(ws + 12800000);      // 12.8 MB
  __hip_bfloat16* feat    = (__hip_bfloat16*)(ws + 25600000);      // 25.6 MB
  __hip_bfloat16* eagg_hi = (__hip_bfloat16*)(ws + 51200000);      // 25.6 MB
  __hip_bfloat16* eagg_lo = (__hip_bfloat16*)(ws + 76800000);      // 25.6 MB
  float* el      = (float*)(ws + 102400000);                       // 1.6 MB
  float* er      = (float*)(ws + 104000000);                       // 1.6 MB
  int*   deg3    = (int*)(ws + 105600000);                         // 0.6 MB
  int*   off3    = (int*)(ws + 106200000);                         // 0.6 MB
  int*   cur3    = (int*)(ws + 106800000);                         // 0.6 MB
  int*   csr_src = (int*)(ws + 107400000);                         // 9.6 MB
  __hip_bfloat16* Wf_hi   = (__hip_bfloat16*)(ws + 117000000);     // 68 KB
  __hip_bfloat16* Wf_lo   = (__hip_bfloat16*)(ws + 117100000);     // 68 KB
  float*          Walr    = (float*)(ws + 117200000);              // 8 KB
  __hip_bfloat16* Bs_hi   = (__hip_bfloat16*)(ws + 117300000);     // 64 KB
  __hip_bfloat16* Bs_lo   = (__hip_bfloat16*)(ws + 117400000);     // 64 KB

  // --- CSR build for all 3 paths + h split ---
  hipMemsetAsync(deg3, 0, (size_t)NPATH * N_NODES * sizeof(int), stream);
  hist3_kernel<<<(NPATH * N_EDGES + 255) / 256, 256, 0, stream>>>(ei, deg3);
  scan3_kernel<<<NPATH, 1024, 0, stream>>>(deg3, off3, cur3);
  scatter3_kernel<<<(NPATH * N_EDGES + 255) / 256, 256, 0, stream>>>(ei, cur3, csr_src);
  hsplit_kernel<<<(N_NODES * 128 + 255) / 256, 256, 0, stream>>>(h, h_hi, h_lo);

  for (int p = 0; p < NPATH; p++) {
    const float* W  = fc_w + (size_t)p * 128 * 256;
    const float* Ws = sem_w + (size_t)p * 256 * 128;

    walr_kernel<<<8, 256, 0, stream>>>(W, attn_l + p * 256, attn_r + p * 256, Walr);
    wfrag_kernel<<<17, 256, 0, stream>>>(W, Walr, Wf_hi, Wf_lo);
    bsem_kernel<<<16, 256, 0, stream>>>(Ws, Bs_hi, Bs_lo);

    feat_mfma_kernel<<<N_NODES / 16, 64, 0, stream>>>(
        h_hi, h_lo, Wf_hi, Wf_lo, feat, el, er);
    aggregate_kernel<<<N_NODES, 256, 0, stream>>>(
        csr_src + (size_t)p * N_EDGES, off3 + p * N_NODES, deg3 + p * N_NODES,
        el, er, feat, eagg_hi, eagg_lo);
    sem_mfma_kernel<<<N_NODES / 16, 64, 0, stream>>>(
        eagg_hi, eagg_lo, Bs_hi, Bs_lo, sem_b, out, p);
  }
}